// Round 14
// baseline (2094.073 us; speedup 1.0000x reference)
//
#include <hip/hip_runtime.h>
#include <hip/hip_bf16.h>

#define N_PTS 8192
#define N_SAMP 2048
#define KNN_K 16
#define NBATCH 4
#define BN_M (NBATCH * N_SAMP * KNN_K)  // 131072
#define NROWS (N_SAMP * NBATCH * KNN_K) // 131072 rows of the im2col matrix
#define NKNNBLK 126
#define KNN_WAVES (NKNNBLK * 8)         // 1008
#define NG1BLK 126
#define CHUNK 128                       // samples per publish batch (16 releases)

typedef float f32x2 __attribute__((ext_vector_type(2)));

// u32 max with DPP-shuffled partner (VALU pipe only). bound_ctrl=false +
// old=src: lanes with invalid sources keep their own value (max(v,v)=v, safe).
// NOTE (R5 lesson): bcast15/bcast31 complete the wave reduction ONLY in lanes
// 48..63; consumers need readlane(...,63) (or lane-63 store) for uniformity.
template <int CTRL, int RM>
__device__ __forceinline__ unsigned umax_dpp(unsigned v) {
  unsigned o = (unsigned)__builtin_amdgcn_update_dpp((int)v, (int)v, CTRL, RM, 0xF, false);
  return (o > v) ? o : v;
}

// ---------------------------------------------------------------- fused FPS+kNN+gemm1
// Roles by blockIdx:
//   0..3            : R4-exact FPS, CHUNK=128 batched publish (R13-validated),
//                     progress[b*64] (one cache line per batch).
//   4..129          : kNN. Wave wv=(bid-4)*8+widx handles q4 = wv + k*1008
//                     (per-wave s is monotone -> no head-of-line block).
//                     After writing a query's 16 idx, lane0 RELEASE-stores
//                     qflag[q]=1 (s_waitcnt vmcnt(0) drains the wave's stores).
//   130..255        : gemm1, TWO 256-thread tiles per block (half=tid>>8);
//                     both halves run the identical barrier sequence. Tile
//                     pair p=(bid-130)+k*126 (<512); tile=2p+half. t0 of each
//                     half spins RELAXED on the tile's 8 qflags, barrier, then
//                     every thread one ACQUIRE load (FPS->kNN->gemm1 release/
//                     acquire chain => knn_idx AND new_xyz visible).
// Deadlock-free: 256 blocks all resident (1/CU at 128KB LDS); producers never
// wait on consumers. y1/stats1 -> gemm2 handoff via kernel boundary.
__global__ __launch_bounds__(512) void fused_fps_knn(
    const float* __restrict__ xyz, const float* __restrict__ feat,
    const float* __restrict__ W1, float* __restrict__ new_xyz,
    int* __restrict__ knn_idx, int* __restrict__ progress,
    int* __restrict__ qflag, float* __restrict__ y1, float* __restrict__ stats1) {
#pragma clang fp contract(off)
  __shared__ __align__(16) float smem[32768];  // 128KB arena (FPS xyzw | gemm1 dual-tile)
  __shared__ unsigned redbuf[8];
  __shared__ unsigned winslot[2];
  __shared__ int sampwin[CHUNK];
  const int bid = blockIdx.x;
  const int tid = threadIdx.x;
  const int lane = tid & 63;

  if (bid < NBATCH) {
    // ---------------- FPS role (R13-validated) ----------------
    float* xyzw = smem;
    const int b = bid;
    const int wid = tid >> 6;
    const float* base = xyz + (size_t)b * N_PTS * 3;
    for (int i = tid; i < N_PTS * 3; i += 512) {
      float v = base[i];
      int p = i / 3, c = i - p * 3;
      xyzw[p * 4 + c] = v;
    }
    for (int i = tid; i < N_PTS; i += 512) xyzw[i * 4 + 3] = 0.f;
    if (tid == 0) { winslot[0] = 0u; winslot[1] = 0xFFFFFFFFu; }
    __syncthreads();

    f32x2 px[8], py[8], pz[8], dmin[8];
#pragma unroll
    for (int j = 0; j < 8; ++j) {
      int p0 = (2 * j) * 512 + tid, p1 = p0 + 512;
      const float4 a = *reinterpret_cast<const float4*>(&xyzw[p0 * 4]);
      const float4 c = *reinterpret_cast<const float4*>(&xyzw[p1 * 4]);
      px[j] = f32x2{a.x, c.x};
      py[j] = f32x2{a.y, c.y};
      pz[j] = f32x2{a.z, c.z};
      dmin[j] = f32x2{1e10f, 1e10f};
    }
    for (int it = 1; it < N_SAMP; ++it) {
      const int p = it & 1;
      const unsigned cur = winslot[p ^ 1];  // sample it-1
      if (tid == 0) sampwin[(it - 1) & (CHUNK - 1)] = (int)cur;
      const bool pub = (it & (CHUNK - 1)) == 0;
      if (pub && tid < CHUNK) {
        const int idx = (tid == CHUNK - 1) ? (int)cur : sampwin[tid];
        const float4 c4 = *reinterpret_cast<const float4*>(&xyzw[idx * 4]);
        float* dst = new_xyz + ((size_t)b * N_SAMP + (it - CHUNK) + tid) * 3;
        dst[0] = c4.x; dst[1] = c4.y; dst[2] = c4.z;
      }
      const float4 c4 = *reinterpret_cast<const float4*>(&xyzw[cur * 4]);
      f32x2 cX = {c4.x, c4.x}, cY = {c4.y, c4.y}, cZ = {c4.z, c4.z};
#pragma unroll
      for (int j = 0; j < 8; ++j) {
        // match reference: sub, square, left-assoc add; contraction OFF
        f32x2 dx = px[j] - cX;
        f32x2 dy = py[j] - cY;
        f32x2 dz = pz[j] - cZ;
        f32x2 s01 = dx * dx + dy * dy;
        f32x2 d = s01 + dz * dz;
        dmin[j].x = fminf(dmin[j].x, d.x);
        dmin[j].y = fminf(dmin[j].y, d.y);
      }
      f32x2 m0 = {fmaxf(dmin[0].x, dmin[1].x), fmaxf(dmin[0].y, dmin[1].y)};
      f32x2 m1 = {fmaxf(dmin[2].x, dmin[3].x), fmaxf(dmin[2].y, dmin[3].y)};
      f32x2 m2 = {fmaxf(dmin[4].x, dmin[5].x), fmaxf(dmin[4].y, dmin[5].y)};
      f32x2 m3 = {fmaxf(dmin[6].x, dmin[7].x), fmaxf(dmin[6].y, dmin[7].y)};
      f32x2 n0 = {fmaxf(m0.x, m1.x), fmaxf(m0.y, m1.y)};
      f32x2 n1 = {fmaxf(m2.x, m3.x), fmaxf(m2.y, m3.y)};
      f32x2 nn = {fmaxf(n0.x, n1.x), fmaxf(n0.y, n1.y)};
      const unsigned bd = __float_as_uint(fmaxf(nn.x, nn.y));
      unsigned r = bd;
      r = umax_dpp<0xB1, 0xF>(r);
      r = umax_dpp<0x4E, 0xF>(r);
      r = umax_dpp<0x124, 0xF>(r);
      r = umax_dpp<0x128, 0xF>(r);
      r = umax_dpp<0x142, 0xA>(r);
      r = umax_dpp<0x143, 0xC>(r);
      if (lane == 63) redbuf[wid] = r;
      __syncthreads();  // barrier A — drains publish stores of ALL waves to L2
      if (tid == 0) {
        winslot[p ^ 1] = 0xFFFFFFFFu;
        if (pub)
          __hip_atomic_store(&progress[b * 64], it, __ATOMIC_RELEASE, __HIP_MEMORY_SCOPE_AGENT);
      }
      unsigned g = redbuf[lane & 7];
      g = umax_dpp<0xB1, 0xF>(g);
      g = umax_dpp<0x4E, 0xF>(g);
      g = umax_dpp<0x124, 0xF>(g);
      if (bd == g) {  // rare: this thread holds the global max
        unsigned cand = 0xFFFFFFFFu;
#pragma unroll
        for (int j = 7; j >= 0; --j) {  // descending => lowest idx wins
          if (__float_as_uint(dmin[j].y) == g) cand = (unsigned)((2 * j + 1) * 512 + tid);
          if (__float_as_uint(dmin[j].x) == g) cand = (unsigned)((2 * j) * 512 + tid);
        }
        atomicMin(&winslot[p], cand);
      }
      __syncthreads();  // barrier B
    }
    {
      const unsigned last = winslot[(N_SAMP - 1) & 1];
      if (tid < CHUNK) {
        const int idx = (tid == CHUNK - 1) ? (int)last : sampwin[tid];
        const float4 c4 = *reinterpret_cast<const float4*>(&xyzw[idx * 4]);
        float* dst = new_xyz + ((size_t)b * N_SAMP + (N_SAMP - CHUNK) + tid) * 3;
        dst[0] = c4.x; dst[1] = c4.y; dst[2] = c4.z;
      }
      __syncthreads();
      if (tid == 0)
        __hip_atomic_store(&progress[b * 64], N_SAMP, __ATOMIC_RELEASE, __HIP_MEMORY_SCOPE_AGENT);
    }
  } else if (bid < NBATCH + NKNNBLK) {
    // ---------------- kNN role ----------------
    const int wv = (bid - NBATCH) * 8 + (tid >> 6);
    for (int q4 = wv; q4 < NBATCH * N_SAMP; q4 += KNN_WAVES) {
      const int b = q4 & 3, s = q4 >> 2;
      while (__hip_atomic_load(&progress[b * 64], __ATOMIC_RELAXED, __HIP_MEMORY_SCOPE_AGENT) <= s)
        __builtin_amdgcn_s_sleep(64);
      (void)__hip_atomic_load(&progress[b * 64], __ATOMIC_ACQUIRE, __HIP_MEMORY_SCOPE_AGENT);
      const int q = b * N_SAMP + s;
      const float* qp = new_xyz + (size_t)q * 3;
      float q0 = qp[0], q1 = qp[1], q2 = qp[2];
      float qn = __fadd_rn(__fadd_rn(__fmul_rn(q0, q0), __fmul_rn(q1, q1)), __fmul_rn(q2, q2));
      const float* pb = xyz + (size_t)b * N_PTS * 3;
      unsigned long long arr[16];
#pragma unroll
      for (int i = 0; i < 16; ++i) arr[i] = ~0ull;
      for (int p = lane; p < N_PTS; p += 64) {
        float p0 = pb[p * 3 + 0], p1 = pb[p * 3 + 1], p2 = pb[p * 3 + 2];
        float pn = __fadd_rn(__fadd_rn(__fmul_rn(p0, p0), __fmul_rn(p1, p1)), __fmul_rn(p2, p2));
        float dt = fmaf(q2, p2, fmaf(q1, p1, __fmul_rn(q0, p0)));
        float d = __fsub_rn(__fadd_rn(qn, pn), __fmul_rn(2.0f, dt));
        unsigned ub = __float_as_uint(d);
        ub ^= (unsigned)((int)ub >> 31) | 0x80000000u;  // order-preserving map
        unsigned long long key = ((unsigned long long)ub << 32) | (unsigned)p;
        if (key < arr[15]) {
          unsigned long long curk = key;
#pragma unroll
          for (int j = 0; j < 16; ++j) {
            unsigned long long lo = (curk < arr[j]) ? curk : arr[j];
            unsigned long long hi = (curk < arr[j]) ? arr[j] : curk;
            arr[j] = lo; curk = hi;
          }
        }
      }
      for (int r = 0; r < KNN_K; ++r) {
        unsigned long long m = arr[0];
#pragma unroll
        for (int o = 32; o > 0; o >>= 1) {
          unsigned long long other = __shfl_xor(m, o, 64);
          m = (other < m) ? other : m;
        }
        if (arr[0] == m) {
#pragma unroll
          for (int j = 0; j < 15; ++j) arr[j] = arr[j + 1];
          arr[15] = ~0ull;
        }
        if (lane == r) knn_idx[(size_t)q * KNN_K + r] = (int)(m & 0xFFFFFFFFu);
      }
      // publish this query's rows (vmcnt(0) before release drains wave stores)
      if (lane == 0)
        __hip_atomic_store(&qflag[q], 1, __ATOMIC_RELEASE, __HIP_MEMORY_SCOPE_AGENT);
    }
  } else {
    // ---------------- gemm1 role (two 256-thread tiles per block) ----------
    const int half = tid >> 8, t = tid & 255;
    float* At = smem + half * 8576;            // [67][128]
    float* Wq = smem + 17152 + half * 2176;    // [17][128]
    float* part = smem + 21504 + half * 1024;  // [4][256]
    int* nb = reinterpret_cast<int*>(smem + 23552) + half * 128;
    for (int pidx = bid - (NBATCH + NKNNBLK); pidx < 512; pidx += NG1BLK) {
      const int tile = 2 * pidx + half;
      const int row0 = tile * 128;
      const int smp0 = tile * 8;
      if (t == 0) {  // spin until this tile's 8 samples have kNN done
        for (int ss = 0; ss < 8; ++ss)
          while (__hip_atomic_load(&qflag[smp0 + ss], __ATOMIC_RELAXED,
                                   __HIP_MEMORY_SCOPE_AGENT) == 0)
            __builtin_amdgcn_s_sleep(32);
      }
      __syncthreads();
      // per-thread acquire: pairs with kNN's release; chain FPS->kNN->here
      // makes knn_idx AND new_xyz visible to every thread.
      (void)__hip_atomic_load(&qflag[smp0], __ATOMIC_ACQUIRE, __HIP_MEMORY_SCOPE_AGENT);
      if (t < 128) nb[t] = knn_idx[row0 + t];
      __syncthreads();
      {
        const int r = t >> 1, q = t & 1;
        const int rg = row0 + r, bs = rg >> 4, b = bs >> 11;
        const float* fr = feat + ((size_t)b * N_PTS + nb[r]) * 64 + q * 32;
#pragma unroll
        for (int i = 0; i < 8; ++i) {
          float4 v = *reinterpret_cast<const float4*>(fr + 4 * i);
          int c = q * 32 + 4 * i;
          At[(c + 0) * 128 + r] = v.x; At[(c + 1) * 128 + r] = v.y;
          At[(c + 2) * 128 + r] = v.z; At[(c + 3) * 128 + r] = v.w;
        }
        if (q == 0) {
          const float* pr = xyz + ((size_t)b * N_PTS + nb[r]) * 3;
          const float* qr = new_xyz + (size_t)bs * 3;
          At[64 * 128 + r] = pr[0] - qr[0];
          At[65 * 128 + r] = pr[1] - qr[1];
          At[66 * 128 + r] = pr[2] - qr[2];
        }
      }
      float acc[8][8];
#pragma unroll
      for (int i = 0; i < 8; ++i)
#pragma unroll
        for (int j = 0; j < 8; ++j) acc[i][j] = 0.f;
      const int ry = t >> 4, cx = t & 15;
      for (int kq = 0; kq < 4; ++kq) {
        const int kbase = kq * 17;
        const int nk = (67 - kbase) < 17 ? (67 - kbase) : 17;
        __syncthreads();
        for (int i = t; i < nk * 32; i += 256)
          reinterpret_cast<float4*>(Wq)[i] =
              reinterpret_cast<const float4*>(W1 + (size_t)kbase * 128)[i];
        __syncthreads();
        for (int kk = 0; kk < nk; ++kk) {
          const float4 a0 = *reinterpret_cast<const float4*>(&At[(kbase + kk) * 128 + ry * 8]);
          const float4 a1 = *reinterpret_cast<const float4*>(&At[(kbase + kk) * 128 + ry * 8 + 4]);
          const float4 w0 = *reinterpret_cast<const float4*>(&Wq[kk * 128 + cx * 8]);
          const float4 w1 = *reinterpret_cast<const float4*>(&Wq[kk * 128 + cx * 8 + 4]);
          const float a[8] = {a0.x, a0.y, a0.z, a0.w, a1.x, a1.y, a1.z, a1.w};
          const float w[8] = {w0.x, w0.y, w0.z, w0.w, w1.x, w1.y, w1.z, w1.w};
#pragma unroll
          for (int i = 0; i < 8; ++i)
#pragma unroll
            for (int j = 0; j < 8; ++j) acc[i][j] = fmaf(a[i], w[j], acc[i][j]);
        }
      }
#pragma unroll
      for (int i = 0; i < 8; ++i) {
        float4 v0 = {acc[i][0], acc[i][1], acc[i][2], acc[i][3]};
        float4 v1 = {acc[i][4], acc[i][5], acc[i][6], acc[i][7]};
        float* dst = y1 + ((size_t)row0 + ry * 8 + i) * 128 + cx * 8;
        *reinterpret_cast<float4*>(dst) = v0;
        *reinterpret_cast<float4*>(dst + 4) = v1;
      }
      float s8[8], q8[8];
#pragma unroll
      for (int j = 0; j < 8; ++j) {
        s8[j] = 0.f; q8[j] = 0.f;
#pragma unroll
        for (int i = 0; i < 8; ++i) { s8[j] += acc[i][j]; q8[j] += acc[i][j] * acc[i][j]; }
      }
#pragma unroll
      for (int j = 0; j < 8; ++j) {
        s8[j] += __shfl_xor(s8[j], 16, 64); q8[j] += __shfl_xor(q8[j], 16, 64);
        s8[j] += __shfl_xor(s8[j], 32, 64); q8[j] += __shfl_xor(q8[j], 32, 64);
      }
      const int w = t >> 6, ln = t & 63;
      if (ln < 16) {
#pragma unroll
        for (int j = 0; j < 8; ++j) {
          part[w * 256 + ln * 8 + j] = s8[j];
          part[w * 256 + 128 + ln * 8 + j] = q8[j];
        }
      }
      __syncthreads();
      {
        int ch = t & 127, which = t >> 7;
        float v = part[0 * 256 + which * 128 + ch] + part[1 * 256 + which * 128 + ch] +
                  part[2 * 256 + which * 128 + ch] + part[3 * 256 + which * 128 + ch];
        atomicAdd(&stats1[which * 128 + ch], v);
      }
      __syncthreads();  // LDS safe to restage next tile
    }
  }
}

// gemm2 v2 (R13-validated): matmul + per-sample MAX/MIN epilogue + stats2.
__global__ __launch_bounds__(256) void gemm2_kernel(
    const float* __restrict__ y1, const float* __restrict__ W2,
    const float* __restrict__ stats1, const float* __restrict__ g1v,
    const float* __restrict__ b1v, float* __restrict__ ymax, float* __restrict__ ymin,
    float* __restrict__ stats2) {
  __shared__ __align__(16) float Ah[64 * 128];
  __shared__ __align__(16) float Wq[32 * 128];
  __shared__ float part[4 * 256];
  __shared__ float s1[128], h1[128];
  const int t = threadIdx.x, blk = blockIdx.x;
  const int row0 = blk * 128;
  const float inv_m = 1.0f / (float)BN_M;
  if (t < 128) {
    float m = stats1[t] * inv_m;
    float var = stats1[128 + t] * inv_m - m * m;
    float rs = rsqrtf(var + 1e-5f);
    float sc = rs * g1v[t];
    s1[t] = sc;
    h1[t] = b1v[t] - m * sc;
  }
  float acc[8][8];
#pragma unroll
  for (int i = 0; i < 8; ++i)
#pragma unroll
    for (int j = 0; j < 8; ++j) acc[i][j] = 0.f;
  const int ry = t >> 4, cx = t & 15;
  for (int kh = 0; kh < 2; ++kh) {
    __syncthreads();
    {
      const int r = t >> 1, q = t & 1;
      const float* src = y1 + ((size_t)row0 + r) * 128 + kh * 64 + q * 32;
#pragma unroll
      for (int i = 0; i < 8; ++i) {
        float4 v = *reinterpret_cast<const float4*>(src + 4 * i);
        int c = kh * 64 + q * 32 + 4 * i;
        int cl = c - kh * 64;
        Ah[(cl + 0) * 128 + r] = fmaxf(fmaf(v.x, s1[c + 0], h1[c + 0]), 0.f);
        Ah[(cl + 1) * 128 + r] = fmaxf(fmaf(v.y, s1[c + 1], h1[c + 1]), 0.f);
        Ah[(cl + 2) * 128 + r] = fmaxf(fmaf(v.z, s1[c + 2], h1[c + 2]), 0.f);
        Ah[(cl + 3) * 128 + r] = fmaxf(fmaf(v.w, s1[c + 3], h1[c + 3]), 0.f);
      }
    }
    for (int kq = 0; kq < 2; ++kq) {
      __syncthreads();
      const int kbase = kh * 64 + kq * 32;
      for (int i = t; i < 32 * 32; i += 256)
        reinterpret_cast<float4*>(Wq)[i] =
            reinterpret_cast<const float4*>(W2 + (size_t)kbase * 128)[i];
      __syncthreads();
      for (int kk = 0; kk < 32; ++kk) {
        const int kl = kq * 32 + kk;
        const float4 a0 = *reinterpret_cast<const float4*>(&Ah[kl * 128 + ry * 8]);
        const float4 a1 = *reinterpret_cast<const float4*>(&Ah[kl * 128 + ry * 8 + 4]);
        const float4 w0 = *reinterpret_cast<const float4*>(&Wq[kk * 128 + cx * 8]);
        const float4 w1 = *reinterpret_cast<const float4*>(&Wq[kk * 128 + cx * 8 + 4]);
        const float a[8] = {a0.x, a0.y, a0.z, a0.w, a1.x, a1.y, a1.z, a1.w};
        const float w[8] = {w0.x, w0.y, w0.z, w0.w, w1.x, w1.y, w1.z, w1.w};
#pragma unroll
        for (int i = 0; i < 8; ++i)
#pragma unroll
          for (int j = 0; j < 8; ++j) acc[i][j] = fmaf(a[i], w[j], acc[i][j]);
      }
    }
  }
  float mx[8], mn[8];
#pragma unroll
  for (int j = 0; j < 8; ++j) { mx[j] = acc[0][j]; mn[j] = acc[0][j]; }
#pragma unroll
  for (int i = 1; i < 8; ++i)
#pragma unroll
    for (int j = 0; j < 8; ++j) {
      mx[j] = fmaxf(mx[j], acc[i][j]);
      mn[j] = fminf(mn[j], acc[i][j]);
    }
#pragma unroll
  for (int j = 0; j < 8; ++j) {
    mx[j] = fmaxf(mx[j], __shfl_xor(mx[j], 16, 64));
    mn[j] = fminf(mn[j], __shfl_xor(mn[j], 16, 64));
  }
  if ((ry & 1) == 0) {
    const int smp = blk * 8 + (ry >> 1);
    float4 a0 = {mx[0], mx[1], mx[2], mx[3]}, a1 = {mx[4], mx[5], mx[6], mx[7]};
    float4 b0 = {mn[0], mn[1], mn[2], mn[3]}, b1 = {mn[4], mn[5], mn[6], mn[7]};
    float* dm = ymax + (size_t)smp * 128 + cx * 8;
    *reinterpret_cast<float4*>(dm) = a0; *reinterpret_cast<float4*>(dm + 4) = a1;
    float* dn = ymin + (size_t)smp * 128 + cx * 8;
    *reinterpret_cast<float4*>(dn) = b0; *reinterpret_cast<float4*>(dn + 4) = b1;
  }
  float s8[8], q8[8];
#pragma unroll
  for (int j = 0; j < 8; ++j) {
    s8[j] = 0.f; q8[j] = 0.f;
#pragma unroll
    for (int i = 0; i < 8; ++i) { s8[j] += acc[i][j]; q8[j] += acc[i][j] * acc[i][j]; }
  }
#pragma unroll
  for (int j = 0; j < 8; ++j) {
    s8[j] += __shfl_xor(s8[j], 16, 64); q8[j] += __shfl_xor(q8[j], 16, 64);
    s8[j] += __shfl_xor(s8[j], 32, 64); q8[j] += __shfl_xor(q8[j], 32, 64);
  }
  const int w = t >> 6, lane = t & 63;
  if (lane < 16) {
#pragma unroll
    for (int j = 0; j < 8; ++j) {
      part[w * 256 + lane * 8 + j] = s8[j];
      part[w * 256 + 128 + lane * 8 + j] = q8[j];
    }
  }
  __syncthreads();
  {
    int ch = t & 127, which = t >> 7;
    float v = part[0 * 256 + which * 128 + ch] + part[1 * 256 + which * 128 + ch] +
              part[2 * 256 + which * 128 + ch] + part[3 * 256 + which * 128 + ch];
    atomicAdd(&stats2[which * 128 + ch], v);
  }
}

// pool v2 (R13-validated): out = relu(sc * (sc>0 ? ymax : ymin) + h).
__global__ __launch_bounds__(256) void pool_kernel(
    const float* __restrict__ ymax, const float* __restrict__ ymin,
    const float* __restrict__ stats2, const float* __restrict__ g2v,
    const float* __restrict__ b2v, float* __restrict__ out_feat) {
  const int idx = blockIdx.x * 256 + threadIdx.x;
  const int ch = idx & 127;
  const float inv_m = 1.0f / (float)BN_M;
  float m = stats2[ch] * inv_m;
  float var = stats2[128 + ch] * inv_m - m * m;
  float rs = rsqrtf(var + 1e-5f);
  float sc = rs * g2v[ch];
  float h = b2v[ch] - m * sc;
  float v = (sc > 0.f) ? ymax[idx] : ymin[idx];
  out_feat[idx] = fmaxf(fmaf(v, sc, h), 0.f);
}

extern "C" void kernel_launch(void* const* d_in, const int* in_sizes, int n_in,
                              void* d_out, int out_size, void* d_ws, size_t ws_size,
                              hipStream_t stream) {
  const float* xyz  = (const float*)d_in[0];
  const float* feat = (const float*)d_in[1];
  const float* W1   = (const float*)d_in[2];
  const float* g1   = (const float*)d_in[3];
  const float* b1   = (const float*)d_in[4];
  const float* W2   = (const float*)d_in[5];
  const float* g2   = (const float*)d_in[6];
  const float* b2   = (const float*)d_in[7];
  float* out = (float*)d_out;
  float* new_xyz = out;                              // [4,2048,3]
  float* out_feat = out + NBATCH * N_SAMP * 3;       // [4,2048,128]

  int* fps_i = (int*)d_ws;                           // [8192] (layout keep)
  int* knn_i = fps_i + NBATCH * N_SAMP;              // [131072]
  float* stats1 = (float*)(knn_i + NROWS);           // [256]
  float* stats2 = stats1 + 256;                      // [256]
  int* progress = (int*)(stats2 + 256);              // [256] (4 used, stride 64)
  int* qflag = progress + 256;                       // [8192]
  float* y1 = (float*)(qflag + 8192);                // [131072*128]
  float* ymax = y1 + (size_t)NROWS * 128;            // [8192*128]
  float* ymin = ymax + (size_t)NBATCH * N_SAMP * 128;// [8192*128]

  // zero stats1, stats2, progress, qflag in one shot (contiguous)
  hipMemsetAsync(stats1, 0, (256 + 256 + 256 + 8192) * sizeof(float), stream);
  hipLaunchKernelGGL(fused_fps_knn, dim3(NBATCH + NKNNBLK + NG1BLK), dim3(512), 0, stream,
                     xyz, feat, W1, new_xyz, knn_i, progress, qflag, y1, stats1);
  hipLaunchKernelGGL(gemm2_kernel, dim3(NROWS / 128), dim3(256), 0, stream,
                     y1, W2, stats1, g1, b1, ymax, ymin, stats2);
  hipLaunchKernelGGL(pool_kernel, dim3(NBATCH * N_SAMP * 128 / 256), dim3(256), 0, stream,
                     ymax, ymin, stats2, g2, b2, out_feat);
}

// Round 15
// 2034.425 us; speedup vs baseline: 1.0293x; 1.0293x over previous
//
#include <hip/hip_runtime.h>
#include <hip/hip_bf16.h>

#define N_PTS 8192
#define N_SAMP 2048
#define KNN_K 16
#define NBATCH 4
#define BN_M (NBATCH * N_SAMP * KNN_K)  // 131072
#define NROWS (N_SAMP * NBATCH * KNN_K) // 131072 rows of the im2col matrix
#define KNN_WAVES 2016                  // 252 spinner blocks * 8 waves
#define CHUNK 128                       // samples per publish batch (16 releases)

typedef float f32x2 __attribute__((ext_vector_type(2)));

// u32 max with DPP-shuffled partner (VALU pipe only). bound_ctrl=false +
// old=src: lanes with invalid sources keep their own value (max(v,v)=v, safe).
// NOTE (R5 lesson): bcast15/bcast31 complete the wave reduction ONLY in lanes
// 48..63; consumers need readlane(...,63) (or lane-63 store) for uniformity.
template <int CTRL, int RM>
__device__ __forceinline__ unsigned umax_dpp(unsigned v) {
  unsigned o = (unsigned)__builtin_amdgcn_update_dpp((int)v, (int)v, CTRL, RM, 0xF, false);
  return (o > v) ? o : v;
}

// ---------------------------------------------------------------- fused FPS+kNN (R13-exact)
// Blocks 0..3: R4-exact FPS, CHUNK=128 batched publish. Publish iters have
// it&127==0 so tid0's ring write targets slot 127 only (readers use slots
// 0..126 + in-register cur for 127). 16 agent releases total.
// Blocks 4..255: RELAXED poll (+s_sleep) then one ACQUIRE before reading
// coords; R1-validated 1-wave kNN scan. Deadlock-free: FPS blocks dispatch
// first (1 block/CU), never wait on spinners.
// R14 lesson: do NOT fuse gemm1 here — its 134MB traffic contends with the
// latency-critical FPS loop (+110µs) and loses more than the dispatch saves.
__global__ __launch_bounds__(512) void fused_fps_knn(
    const float* __restrict__ xyz, float* __restrict__ new_xyz,
    int* __restrict__ knn_idx, int* __restrict__ progress) {
#pragma clang fp contract(off)
  __shared__ __align__(16) float xyzw[N_PTS * 4];
  __shared__ unsigned redbuf[8];
  __shared__ unsigned winslot[2];
  __shared__ int sampwin[CHUNK];
  const int tid = threadIdx.x;
  const int lane = tid & 63;

  if (blockIdx.x < NBATCH) {
    // ---------------- FPS role ----------------
    const int b = blockIdx.x;
    const int wid = tid >> 6;
    const float* base = xyz + (size_t)b * N_PTS * 3;
    for (int i = tid; i < N_PTS * 3; i += 512) {
      float v = base[i];
      int p = i / 3, c = i - p * 3;
      xyzw[p * 4 + c] = v;
    }
    for (int i = tid; i < N_PTS; i += 512) xyzw[i * 4 + 3] = 0.f;
    if (tid == 0) { winslot[0] = 0u; winslot[1] = 0xFFFFFFFFu; }
    __syncthreads();

    // point k (k=0..15) of this thread is index k*512+tid; pair j = k=2j,2j+1
    f32x2 px[8], py[8], pz[8], dmin[8];
#pragma unroll
    for (int j = 0; j < 8; ++j) {
      int p0 = (2 * j) * 512 + tid, p1 = p0 + 512;
      const float4 a = *reinterpret_cast<const float4*>(&xyzw[p0 * 4]);
      const float4 c = *reinterpret_cast<const float4*>(&xyzw[p1 * 4]);
      px[j] = f32x2{a.x, c.x};
      py[j] = f32x2{a.y, c.y};
      pz[j] = f32x2{a.z, c.z};
      dmin[j] = f32x2{1e10f, 1e10f};
    }
    for (int it = 1; it < N_SAMP; ++it) {
      const int p = it & 1;
      const unsigned cur = winslot[p ^ 1];  // sample it-1
      if (tid == 0) sampwin[(it - 1) & (CHUNK - 1)] = (int)cur;
      const bool pub = (it & (CHUNK - 1)) == 0;  // publish samples it-128..it-1
      if (pub && tid < CHUNK) {
        // slot CHUNK-1 is being written this iter by tid0; its value IS cur.
        const int idx = (tid == CHUNK - 1) ? (int)cur : sampwin[tid];
        const float4 c4 = *reinterpret_cast<const float4*>(&xyzw[idx * 4]);
        float* dst = new_xyz + ((size_t)b * N_SAMP + (it - CHUNK) + tid) * 3;
        dst[0] = c4.x; dst[1] = c4.y; dst[2] = c4.z;
      }
      const float4 c4 = *reinterpret_cast<const float4*>(&xyzw[cur * 4]);
      f32x2 cX = {c4.x, c4.x}, cY = {c4.y, c4.y}, cZ = {c4.z, c4.z};
#pragma unroll
      for (int j = 0; j < 8; ++j) {
        // match reference: sub, square, left-assoc add; contraction OFF
        f32x2 dx = px[j] - cX;
        f32x2 dy = py[j] - cY;
        f32x2 dz = pz[j] - cZ;
        f32x2 s01 = dx * dx + dy * dy;
        f32x2 d = s01 + dz * dz;
        dmin[j].x = fminf(dmin[j].x, d.x);
        dmin[j].y = fminf(dmin[j].y, d.y);
      }
      // thread-local max (value only; index recovered by exception below)
      f32x2 m0 = {fmaxf(dmin[0].x, dmin[1].x), fmaxf(dmin[0].y, dmin[1].y)};
      f32x2 m1 = {fmaxf(dmin[2].x, dmin[3].x), fmaxf(dmin[2].y, dmin[3].y)};
      f32x2 m2 = {fmaxf(dmin[4].x, dmin[5].x), fmaxf(dmin[4].y, dmin[5].y)};
      f32x2 m3 = {fmaxf(dmin[6].x, dmin[7].x), fmaxf(dmin[6].y, dmin[7].y)};
      f32x2 n0 = {fmaxf(m0.x, m1.x), fmaxf(m0.y, m1.y)};
      f32x2 n1 = {fmaxf(m2.x, m3.x), fmaxf(m2.y, m3.y)};
      f32x2 nn = {fmaxf(n0.x, n1.x), fmaxf(n0.y, n1.y)};
      const unsigned bd = __float_as_uint(fmaxf(nn.x, nn.y));
      // wave max: xor1, xor2, ror4, ror8, bcast15, bcast31 -> lane63
      unsigned r = bd;
      r = umax_dpp<0xB1, 0xF>(r);
      r = umax_dpp<0x4E, 0xF>(r);
      r = umax_dpp<0x124, 0xF>(r);
      r = umax_dpp<0x128, 0xF>(r);
      r = umax_dpp<0x142, 0xA>(r);
      r = umax_dpp<0x143, 0xC>(r);
      if (lane == 63) redbuf[wid] = r;
      __syncthreads();  // barrier A — drains publish stores of ALL waves to L2
      if (tid == 0) {
        winslot[p ^ 1] = 0xFFFFFFFFu;  // reset for iter it+1's atomicMin
        if (pub)  // writeback L2 (agent release) then store progress
          __hip_atomic_store(&progress[b], it, __ATOMIC_RELEASE, __HIP_MEMORY_SCOPE_AGENT);
      }
      // combine 8 wave maxima: period-8; xor1+xor2+ror4 => uniform
      unsigned g = redbuf[lane & 7];
      g = umax_dpp<0xB1, 0xF>(g);
      g = umax_dpp<0x4E, 0xF>(g);
      g = umax_dpp<0x124, 0xF>(g);
      if (bd == g) {  // rare: this thread holds the global max
        unsigned cand = 0xFFFFFFFFu;
#pragma unroll
        for (int j = 7; j >= 0; --j) {  // descending => lowest idx wins
          if (__float_as_uint(dmin[j].y) == g) cand = (unsigned)((2 * j + 1) * 512 + tid);
          if (__float_as_uint(dmin[j].x) == g) cand = (unsigned)((2 * j) * 512 + tid);
        }
        atomicMin(&winslot[p], cand);
      }
      __syncthreads();  // barrier B
    }
    // final chunk: samples 1920..2047 (sampwin slots 0..126 + winner 2047)
    {
      const unsigned last = winslot[(N_SAMP - 1) & 1];
      if (tid < CHUNK) {
        const int idx = (tid == CHUNK - 1) ? (int)last : sampwin[tid];
        const float4 c4 = *reinterpret_cast<const float4*>(&xyzw[idx * 4]);
        float* dst = new_xyz + ((size_t)b * N_SAMP + (N_SAMP - CHUNK) + tid) * 3;
        dst[0] = c4.x; dst[1] = c4.y; dst[2] = c4.z;
      }
      __syncthreads();  // drain final publish stores
      if (tid == 0)
        __hip_atomic_store(&progress[b], N_SAMP, __ATOMIC_RELEASE, __HIP_MEMORY_SCOPE_AGENT);
    }
  } else {
    // ---------------- kNN role (relaxed spin -> one acquire -> scan) -------
    const int wv = (int)(blockIdx.x - NBATCH) * 8 + (tid >> 6);
    for (int q4 = wv; q4 < NBATCH * N_SAMP; q4 += KNN_WAVES) {
      const int b = q4 & 3, s = q4 >> 2;
      while (__hip_atomic_load(&progress[b], __ATOMIC_RELAXED, __HIP_MEMORY_SCOPE_AGENT) <= s)
        __builtin_amdgcn_s_sleep(64);
      // one acquire (cache invalidate) so new_xyz reads aren't stale
      (void)__hip_atomic_load(&progress[b], __ATOMIC_ACQUIRE, __HIP_MEMORY_SCOPE_AGENT);
      const int q = b * N_SAMP + s;
      const float* qp = new_xyz + (size_t)q * 3;
      float q0 = qp[0], q1 = qp[1], q2 = qp[2];
      float qn = __fadd_rn(__fadd_rn(__fmul_rn(q0, q0), __fmul_rn(q1, q1)), __fmul_rn(q2, q2));
      const float* pb = xyz + (size_t)b * N_PTS * 3;
      unsigned long long arr[16];
#pragma unroll
      for (int i = 0; i < 16; ++i) arr[i] = ~0ull;
      for (int p = lane; p < N_PTS; p += 64) {
        float p0 = pb[p * 3 + 0], p1 = pb[p * 3 + 1], p2 = pb[p * 3 + 2];
        float pn = __fadd_rn(__fadd_rn(__fmul_rn(p0, p0), __fmul_rn(p1, p1)), __fmul_rn(p2, p2));
        float dt = fmaf(q2, p2, fmaf(q1, p1, __fmul_rn(q0, p0)));
        float d = __fsub_rn(__fadd_rn(qn, pn), __fmul_rn(2.0f, dt));
        unsigned ub = __float_as_uint(d);
        ub ^= (unsigned)((int)ub >> 31) | 0x80000000u;  // order-preserving map
        unsigned long long key = ((unsigned long long)ub << 32) | (unsigned)p;
        if (key < arr[15]) {
          unsigned long long curk = key;
#pragma unroll
          for (int j = 0; j < 16; ++j) {
            unsigned long long lo = (curk < arr[j]) ? curk : arr[j];
            unsigned long long hi = (curk < arr[j]) ? arr[j] : curk;
            arr[j] = lo; curk = hi;
          }
        }
      }
      for (int r = 0; r < KNN_K; ++r) {
        unsigned long long m = arr[0];
#pragma unroll
        for (int o = 32; o > 0; o >>= 1) {
          unsigned long long other = __shfl_xor(m, o, 64);
          m = (other < m) ? other : m;
        }
        if (arr[0] == m) {
#pragma unroll
          for (int j = 0; j < 15; ++j) arr[j] = arr[j + 1];
          arr[15] = ~0ull;
        }
        if (lane == r) knn_idx[(size_t)q * KNN_K + r] = (int)(m & 0xFFFFFFFFu);
      }
    }
  }
}

// ---------------------------------------------------------------- MLP
// gemm1: unchanged (validated R7).
__global__ __launch_bounds__(256) void gemm1_kernel(
    const float* __restrict__ xyz, const float* __restrict__ feat,
    const float* __restrict__ W1, const float* __restrict__ new_xyz,
    const int* __restrict__ knn_i, float* __restrict__ y1, float* __restrict__ stats1) {
  __shared__ __align__(16) float At[67 * 128];   // A^T[k][row]
  __shared__ __align__(16) float Wq[17 * 128];   // W1 k-quarter
  __shared__ float part[4 * 256];
  __shared__ int nb[128];
  const int t = threadIdx.x, blk = blockIdx.x;
  const int row0 = blk * 128;
  if (t < 128) nb[t] = knn_i[row0 + t];
  __syncthreads();
  {
    const int r = t >> 1, q = t & 1;
    const int rg = row0 + r, bs = rg >> 4, b = bs >> 11;
    const float* fr = feat + ((size_t)b * N_PTS + nb[r]) * 64 + q * 32;
#pragma unroll
    for (int i = 0; i < 8; ++i) {
      float4 v = *reinterpret_cast<const float4*>(fr + 4 * i);
      int c = q * 32 + 4 * i;
      At[(c + 0) * 128 + r] = v.x; At[(c + 1) * 128 + r] = v.y;
      At[(c + 2) * 128 + r] = v.z; At[(c + 3) * 128 + r] = v.w;
    }
    if (q == 0) {
      const float* pr = xyz + ((size_t)b * N_PTS + nb[r]) * 3;
      const float* qr = new_xyz + (size_t)bs * 3;
      At[64 * 128 + r] = pr[0] - qr[0];
      At[65 * 128 + r] = pr[1] - qr[1];
      At[66 * 128 + r] = pr[2] - qr[2];
    }
  }
  float acc[8][8];
#pragma unroll
  for (int i = 0; i < 8; ++i)
#pragma unroll
    for (int j = 0; j < 8; ++j) acc[i][j] = 0.f;
  const int ry = t >> 4, cx = t & 15;
  for (int kq = 0; kq < 4; ++kq) {
    const int kbase = kq * 17;
    const int nk = (67 - kbase) < 17 ? (67 - kbase) : 17;
    __syncthreads();
    for (int i = t; i < nk * 32; i += 256)
      reinterpret_cast<float4*>(Wq)[i] =
          reinterpret_cast<const float4*>(W1 + (size_t)kbase * 128)[i];
    __syncthreads();
    for (int kk = 0; kk < nk; ++kk) {
      const float4 a0 = *reinterpret_cast<const float4*>(&At[(kbase + kk) * 128 + ry * 8]);
      const float4 a1 = *reinterpret_cast<const float4*>(&At[(kbase + kk) * 128 + ry * 8 + 4]);
      const float4 w0 = *reinterpret_cast<const float4*>(&Wq[kk * 128 + cx * 8]);
      const float4 w1 = *reinterpret_cast<const float4*>(&Wq[kk * 128 + cx * 8 + 4]);
      const float a[8] = {a0.x, a0.y, a0.z, a0.w, a1.x, a1.y, a1.z, a1.w};
      const float w[8] = {w0.x, w0.y, w0.z, w0.w, w1.x, w1.y, w1.z, w1.w};
#pragma unroll
      for (int i = 0; i < 8; ++i)
#pragma unroll
        for (int j = 0; j < 8; ++j) acc[i][j] = fmaf(a[i], w[j], acc[i][j]);
    }
  }
#pragma unroll
  for (int i = 0; i < 8; ++i) {
    float4 v0 = {acc[i][0], acc[i][1], acc[i][2], acc[i][3]};
    float4 v1 = {acc[i][4], acc[i][5], acc[i][6], acc[i][7]};
    float* dst = y1 + ((size_t)row0 + ry * 8 + i) * 128 + cx * 8;
    *reinterpret_cast<float4*>(dst) = v0;
    *reinterpret_cast<float4*>(dst + 4) = v1;
  }
  float s8[8], q8[8];
#pragma unroll
  for (int j = 0; j < 8; ++j) {
    s8[j] = 0.f; q8[j] = 0.f;
#pragma unroll
    for (int i = 0; i < 8; ++i) { s8[j] += acc[i][j]; q8[j] += acc[i][j] * acc[i][j]; }
  }
#pragma unroll
  for (int j = 0; j < 8; ++j) {
    s8[j] += __shfl_xor(s8[j], 16, 64); q8[j] += __shfl_xor(q8[j], 16, 64);
    s8[j] += __shfl_xor(s8[j], 32, 64); q8[j] += __shfl_xor(q8[j], 32, 64);
  }
  const int w = t >> 6, lane = t & 63;
  if (lane < 16) {
#pragma unroll
    for (int j = 0; j < 8; ++j) {
      part[w * 256 + lane * 8 + j] = s8[j];
      part[w * 256 + 128 + lane * 8 + j] = q8[j];
    }
  }
  __syncthreads();
  {
    int ch = t & 127, which = t >> 7;
    float v = part[0 * 256 + which * 128 + ch] + part[1 * 256 + which * 128 + ch] +
              part[2 * 256 + which * 128 + ch] + part[3 * 256 + which * 128 + ch];
    atomicAdd(&stats1[which * 128 + ch], v);
  }
}

// gemm2 v2 (R13-validated): matmul + per-sample MAX/MIN epilogue + stats2.
// BN2+relu+maxpool commute via monotonicity — bit-identical output.
__global__ __launch_bounds__(256) void gemm2_kernel(
    const float* __restrict__ y1, const float* __restrict__ W2,
    const float* __restrict__ stats1, const float* __restrict__ g1v,
    const float* __restrict__ b1v, float* __restrict__ ymax, float* __restrict__ ymin,
    float* __restrict__ stats2) {
  __shared__ __align__(16) float Ah[64 * 128];
  __shared__ __align__(16) float Wq[32 * 128];
  __shared__ float part[4 * 256];
  __shared__ float s1[128], h1[128];
  const int t = threadIdx.x, blk = blockIdx.x;
  const int row0 = blk * 128;
  const float inv_m = 1.0f / (float)BN_M;
  if (t < 128) {
    float m = stats1[t] * inv_m;
    float var = stats1[128 + t] * inv_m - m * m;
    float rs = rsqrtf(var + 1e-5f);
    float sc = rs * g1v[t];
    s1[t] = sc;
    h1[t] = b1v[t] - m * sc;
  }
  float acc[8][8];
#pragma unroll
  for (int i = 0; i < 8; ++i)
#pragma unroll
    for (int j = 0; j < 8; ++j) acc[i][j] = 0.f;
  const int ry = t >> 4, cx = t & 15;
  for (int kh = 0; kh < 2; ++kh) {
    __syncthreads();
    {
      const int r = t >> 1, q = t & 1;
      const float* src = y1 + ((size_t)row0 + r) * 128 + kh * 64 + q * 32;
#pragma unroll
      for (int i = 0; i < 8; ++i) {
        float4 v = *reinterpret_cast<const float4*>(src + 4 * i);
        int c = kh * 64 + q * 32 + 4 * i;
        int cl = c - kh * 64;
        Ah[(cl + 0) * 128 + r] = fmaxf(fmaf(v.x, s1[c + 0], h1[c + 0]), 0.f);
        Ah[(cl + 1) * 128 + r] = fmaxf(fmaf(v.y, s1[c + 1], h1[c + 1]), 0.f);
        Ah[(cl + 2) * 128 + r] = fmaxf(fmaf(v.z, s1[c + 2], h1[c + 2]), 0.f);
        Ah[(cl + 3) * 128 + r] = fmaxf(fmaf(v.w, s1[c + 3], h1[c + 3]), 0.f);
      }
    }
    for (int kq = 0; kq < 2; ++kq) {
      __syncthreads();
      const int kbase = kh * 64 + kq * 32;
      for (int i = t; i < 32 * 32; i += 256)
        reinterpret_cast<float4*>(Wq)[i] =
            reinterpret_cast<const float4*>(W2 + (size_t)kbase * 128)[i];
      __syncthreads();
      for (int kk = 0; kk < 32; ++kk) {
        const int kl = kq * 32 + kk;
        const float4 a0 = *reinterpret_cast<const float4*>(&Ah[kl * 128 + ry * 8]);
        const float4 a1 = *reinterpret_cast<const float4*>(&Ah[kl * 128 + ry * 8 + 4]);
        const float4 w0 = *reinterpret_cast<const float4*>(&Wq[kk * 128 + cx * 8]);
        const float4 w1 = *reinterpret_cast<const float4*>(&Wq[kk * 128 + cx * 8 + 4]);
        const float a[8] = {a0.x, a0.y, a0.z, a0.w, a1.x, a1.y, a1.z, a1.w};
        const float w[8] = {w0.x, w0.y, w0.z, w0.w, w1.x, w1.y, w1.z, w1.w};
#pragma unroll
        for (int i = 0; i < 8; ++i)
#pragma unroll
          for (int j = 0; j < 8; ++j) acc[i][j] = fmaf(a[i], w[j], acc[i][j]);
      }
    }
  }
  // per-thread max/min over 8 rows, then pair-combine (ry,ry^1) via xor-16
  float mx[8], mn[8];
#pragma unroll
  for (int j = 0; j < 8; ++j) { mx[j] = acc[0][j]; mn[j] = acc[0][j]; }
#pragma unroll
  for (int i = 1; i < 8; ++i)
#pragma unroll
    for (int j = 0; j < 8; ++j) {
      mx[j] = fmaxf(mx[j], acc[i][j]);
      mn[j] = fminf(mn[j], acc[i][j]);
    }
#pragma unroll
  for (int j = 0; j < 8; ++j) {
    mx[j] = fmaxf(mx[j], __shfl_xor(mx[j], 16, 64));
    mn[j] = fminf(mn[j], __shfl_xor(mn[j], 16, 64));
  }
  if ((ry & 1) == 0) {
    const int smp = blk * 8 + (ry >> 1);
    float4 a0 = {mx[0], mx[1], mx[2], mx[3]}, a1 = {mx[4], mx[5], mx[6], mx[7]};
    float4 b0 = {mn[0], mn[1], mn[2], mn[3]}, b1 = {mn[4], mn[5], mn[6], mn[7]};
    float* dm = ymax + (size_t)smp * 128 + cx * 8;
    *reinterpret_cast<float4*>(dm) = a0; *reinterpret_cast<float4*>(dm + 4) = a1;
    float* dn = ymin + (size_t)smp * 128 + cx * 8;
    *reinterpret_cast<float4*>(dn) = b0; *reinterpret_cast<float4*>(dn + 4) = b1;
  }
  float s8[8], q8[8];
#pragma unroll
  for (int j = 0; j < 8; ++j) {
    s8[j] = 0.f; q8[j] = 0.f;
#pragma unroll
    for (int i = 0; i < 8; ++i) { s8[j] += acc[i][j]; q8[j] += acc[i][j] * acc[i][j]; }
  }
#pragma unroll
  for (int j = 0; j < 8; ++j) {
    s8[j] += __shfl_xor(s8[j], 16, 64); q8[j] += __shfl_xor(q8[j], 16, 64);
    s8[j] += __shfl_xor(s8[j], 32, 64); q8[j] += __shfl_xor(q8[j], 32, 64);
  }
  const int w = t >> 6, lane = t & 63;
  if (lane < 16) {
#pragma unroll
    for (int j = 0; j < 8; ++j) {
      part[w * 256 + lane * 8 + j] = s8[j];
      part[w * 256 + 128 + lane * 8 + j] = q8[j];
    }
  }
  __syncthreads();
  {
    int ch = t & 127, which = t >> 7;
    float v = part[0 * 256 + which * 128 + ch] + part[1 * 256 + which * 128 + ch] +
              part[2 * 256 + which * 128 + ch] + part[3 * 256 + which * 128 + ch];
    atomicAdd(&stats2[which * 128 + ch], v);
  }
}

// pool v2 (R13-validated): out = relu(sc * (sc>0 ? ymax : ymin) + h).
__global__ __launch_bounds__(256) void pool_kernel(
    const float* __restrict__ ymax, const float* __restrict__ ymin,
    const float* __restrict__ stats2, const float* __restrict__ g2v,
    const float* __restrict__ b2v, float* __restrict__ out_feat) {
  const int idx = blockIdx.x * 256 + threadIdx.x;  // over 8192 samples * 128 ch
  const int ch = idx & 127;
  const float inv_m = 1.0f / (float)BN_M;
  float m = stats2[ch] * inv_m;
  float var = stats2[128 + ch] * inv_m - m * m;
  float rs = rsqrtf(var + 1e-5f);
  float sc = rs * g2v[ch];
  float h = b2v[ch] - m * sc;
  float v = (sc > 0.f) ? ymax[idx] : ymin[idx];
  out_feat[idx] = fmaxf(fmaf(v, sc, h), 0.f);
}

extern "C" void kernel_launch(void* const* d_in, const int* in_sizes, int n_in,
                              void* d_out, int out_size, void* d_ws, size_t ws_size,
                              hipStream_t stream) {
  const float* xyz  = (const float*)d_in[0];
  const float* feat = (const float*)d_in[1];
  const float* W1   = (const float*)d_in[2];
  const float* g1   = (const float*)d_in[3];
  const float* b1   = (const float*)d_in[4];
  const float* W2   = (const float*)d_in[5];
  const float* g2   = (const float*)d_in[6];
  const float* b2   = (const float*)d_in[7];
  float* out = (float*)d_out;
  float* new_xyz = out;                              // [4,2048,3]
  float* out_feat = out + NBATCH * N_SAMP * 3;       // [4,2048,128]

  int* fps_i = (int*)d_ws;                           // [8192] (unused, layout kept)
  int* knn_i = fps_i + NBATCH * N_SAMP;              // [131072]
  float* stats1 = (float*)(knn_i + NROWS);           // [256]
  float* stats2 = stats1 + 256;                      // [256]
  int* progress = (int*)(stats2 + 256);              // [64] (4 used)
  float* y1 = (float*)(progress + 64);               // [131072*128]
  float* ymax = y1 + (size_t)NROWS * 128;            // [8192*128]
  float* ymin = ymax + (size_t)NBATCH * N_SAMP * 128;// [8192*128]

  // zero stats1, stats2, progress in one shot (contiguous)
  hipMemsetAsync(stats1, 0, (256 + 256 + 64) * sizeof(float), stream);
  hipLaunchKernelGGL(fused_fps_knn, dim3(NBATCH + 252), dim3(512), 0, stream,
                     xyz, new_xyz, knn_i, progress);
  hipLaunchKernelGGL(gemm1_kernel, dim3(NROWS / 128), dim3(256), 0, stream,
                     xyz, feat, W1, new_xyz, knn_i, y1, stats1);
  hipLaunchKernelGGL(gemm2_kernel, dim3(NROWS / 128), dim3(256), 0, stream,
                     y1, W2, stats1, g1, b1, ymax, ymin, stats2);
  hipLaunchKernelGGL(pool_kernel, dim3(NBATCH * N_SAMP * 128 / 256), dim3(256), 0, stream,
                     ymax, ymin, stats2, g2, b2, out_feat);
}